// Round 1
// baseline (12738.181 us; speedup 1.0000x reference)
//
#include <hip/hip_runtime.h>
#include <hip/hip_bf16.h>

// LSTM B=64, T=512, I=512, H=1024.
// Strategy: fuse x@W^T into the per-step recurrent kernel (no 512MB pre buffer).
// prep: convert U,W f32->bf16 into ws; zero h(bf16 ping-pong) and c state.
// 512 sequential lstm_step launches; kernel boundary = grid-wide sync.

typedef __attribute__((ext_vector_type(8))) short bf16x8;
typedef __attribute__((ext_vector_type(4))) float f32x4;

static __device__ __forceinline__ unsigned short f2bf(float f) {
    union { float f; unsigned int u; } v; v.f = f;
    unsigned int r = v.u + 0x7fffu + ((v.u >> 16) & 1u);  // RNE
    return (unsigned short)(r >> 16);
}

#define NB   64
#define NT   512
#define NI   512
#define NH   1024

// ---------------- prep: f32 -> bf16 conversions + state zeroing ----------------
__global__ void lstm_prep(const float* __restrict__ Ui, const float* __restrict__ Uf,
                          const float* __restrict__ Uc, const float* __restrict__ Uo,
                          const float* __restrict__ Wi, const float* __restrict__ Wf,
                          const float* __restrict__ Wc, const float* __restrict__ Wo,
                          unsigned short* __restrict__ Ub, unsigned short* __restrict__ Wb,
                          unsigned short* __restrict__ hb0, float* __restrict__ c_state)
{
    const int NU = 4 * NH * NH;        // 4194304
    const int NW = 4 * NH * NI;        // 2097152
    const int NS = NB * NH;            // 65536
    const int total = NU + NW + NS + NS;
    for (int idx = blockIdx.x * blockDim.x + threadIdx.x; idx < total;
         idx += gridDim.x * blockDim.x) {
        if (idx < NU) {
            int g = idx >> 20;
            int off = idx & (NH * NH - 1);
            const float* U = (g == 0) ? Ui : (g == 1) ? Uf : (g == 2) ? Uc : Uo;
            Ub[idx] = f2bf(U[off]);
        } else if (idx < NU + NW) {
            int j = idx - NU;
            int g = j >> 19;
            int off = j & (NH * NI - 1);
            const float* W = (g == 0) ? Wi : (g == 1) ? Wf : (g == 2) ? Wc : Wo;
            Wb[j] = f2bf(W[off]);
        } else if (idx < NU + NW + NS) {
            hb0[idx - NU - NW] = 0;
        } else {
            c_state[idx - NU - NW - NS] = 0.0f;
        }
    }
}

// ---------------- one recurrent step ----------------
// grid = 128 blocks: blockIdx.x = u_tile*2 + b_half  (u_tile in [0,64), b_half in {0,1})
// block = 256 threads = 4 waves; wave w computes gate w for (32 b) x (16 u).
// Fragments loaded directly global->VGPR (no data reuse inside one launch).
__global__ __launch_bounds__(256) void lstm_step(
    const float* __restrict__ x,             // [64][512][512] f32
    const unsigned short* __restrict__ Ub,   // [4][1024][1024] bf16
    const unsigned short* __restrict__ Wb,   // [4][1024][512]  bf16
    const unsigned short* __restrict__ hb_in,  // [64][1024] bf16
    unsigned short* __restrict__ hb_out,       // [64][1024] bf16
    const float* __restrict__ bi, const float* __restrict__ bff,
    const float* __restrict__ bc, const float* __restrict__ bo,
    float* __restrict__ out,       // [64][512][1024] f32
    float* __restrict__ c_state,   // [64][1024] f32 (the c_n region of d_out)
    float* __restrict__ hn_out,    // h_n region (only for t==511), else null
    int t)
{
    __shared__ float gacc[4][32][16];   // gate preactivations exchange (8 KB)

    const int lane = threadIdx.x & 63;
    const int g    = threadIdx.x >> 6;          // gate: 0=i 1=f 2=g 3=o
    const int u0   = (blockIdx.x >> 1) * 16;    // 16 units
    const int b0   = (blockIdx.x & 1) * 32;     // 32 batches
    const int rm   = lane & 15;                 // row (A) / col (B) within fragment
    const int kg   = (lane >> 4) * 8;           // k-group offset (8 contiguous)

    f32x4 acc0 = {0.f, 0.f, 0.f, 0.f};
    f32x4 acc1 = {0.f, 0.f, 0.f, 0.f};

    // ---- recurrent part: sum_k h[b][k] * U_g[u][k], K = 1024 ----
    const unsigned short* Ug  = Ub + (size_t)g * (NH * NH) + (size_t)(u0 + rm) * NH;
    const unsigned short* h0p = hb_in + (size_t)(b0 + rm) * NH;
    const unsigned short* h1p = hb_in + (size_t)(b0 + 16 + rm) * NH;
    #pragma unroll 4
    for (int k0 = 0; k0 < NH; k0 += 32) {
        bf16x8 bfrag = *(const bf16x8*)(Ug + k0 + kg);
        bf16x8 a0 = *(const bf16x8*)(h0p + k0 + kg);
        bf16x8 a1 = *(const bf16x8*)(h1p + k0 + kg);
        acc0 = __builtin_amdgcn_mfma_f32_16x16x32_bf16(a0, bfrag, acc0, 0, 0, 0);
        acc1 = __builtin_amdgcn_mfma_f32_16x16x32_bf16(a1, bfrag, acc1, 0, 0, 0);
    }

    // ---- input part: sum_k x[b][t][k] * W_g[u][k], K = 512 (fp32 x, cvt on the fly) ----
    const unsigned short* Wg  = Wb + (size_t)g * (NH * NI) + (size_t)(u0 + rm) * NI;
    const float* x0p = x + ((size_t)(b0 + rm) * NT + t) * NI;
    const float* x1p = x + ((size_t)(b0 + 16 + rm) * NT + t) * NI;
    #pragma unroll 2
    for (int k0 = 0; k0 < NI; k0 += 32) {
        bf16x8 bfrag = *(const bf16x8*)(Wg + k0 + kg);
        f32x4 lo0 = *(const f32x4*)(x0p + k0 + kg);
        f32x4 hi0 = *(const f32x4*)(x0p + k0 + kg + 4);
        f32x4 lo1 = *(const f32x4*)(x1p + k0 + kg);
        f32x4 hi1 = *(const f32x4*)(x1p + k0 + kg + 4);
        bf16x8 a0, a1;
        #pragma unroll
        for (int j = 0; j < 4; j++) {
            a0[j]     = (short)f2bf(lo0[j]);
            a0[j + 4] = (short)f2bf(hi0[j]);
            a1[j]     = (short)f2bf(lo1[j]);
            a1[j + 4] = (short)f2bf(hi1[j]);
        }
        acc0 = __builtin_amdgcn_mfma_f32_16x16x32_bf16(a0, bfrag, acc0, 0, 0, 0);
        acc1 = __builtin_amdgcn_mfma_f32_16x16x32_bf16(a1, bfrag, acc1, 0, 0, 0);
    }

    // ---- exchange gate values so one thread owns all 4 gates of a (b,u) ----
    // C/D layout (verified): col = lane&15, row = (lane>>4)*4 + reg
    const int row4 = (lane >> 4) * 4;
    #pragma unroll
    for (int r = 0; r < 4; r++) {
        gacc[g][row4 + r][rm]      = acc0[r];
        gacc[g][16 + row4 + r][rm] = acc1[r];
    }
    __syncthreads();

    for (int p = threadIdx.x; p < 512; p += 256) {
        int bl = p >> 4, ul = p & 15;
        int b = b0 + bl, u = u0 + ul;
        float pi = gacc[0][bl][ul] + bi[u];
        float pf = gacc[1][bl][ul] + bff[u];
        float pg = gacc[2][bl][ul] + bc[u];
        float po = gacc[3][bl][ul] + bo[u];
        float ig = 1.f / (1.f + __expf(-pi));
        float fg = 1.f / (1.f + __expf(-pf));
        float gg = tanhf(pg);
        float og = 1.f / (1.f + __expf(-po));
        float cold = c_state[(size_t)b * NH + u];
        float cn = fg * cold + ig * gg;
        float hn = og * tanhf(cn);
        c_state[(size_t)b * NH + u] = cn;
        out[((size_t)b * NT + t) * NH + u] = hn;
        hb_out[(size_t)b * NH + u] = f2bf(hn);
        if (hn_out) hn_out[(size_t)b * NH + u] = hn;
    }
}

extern "C" void kernel_launch(void* const* d_in, const int* in_sizes, int n_in,
                              void* d_out, int out_size, void* d_ws, size_t ws_size,
                              hipStream_t stream) {
    const float* x  = (const float*)d_in[0];
    const float* Wi = (const float*)d_in[1];
    const float* Wf = (const float*)d_in[2];
    const float* Wc = (const float*)d_in[3];
    const float* Wo = (const float*)d_in[4];
    const float* Ui = (const float*)d_in[5];
    const float* Uf = (const float*)d_in[6];
    const float* Uc = (const float*)d_in[7];
    const float* Uo = (const float*)d_in[8];
    const float* bi = (const float*)d_in[9];
    const float* bf = (const float*)d_in[10];
    const float* bc = (const float*)d_in[11];
    const float* bo = (const float*)d_in[12];

    char* ws = (char*)d_ws;
    unsigned short* Ub  = (unsigned short*)ws;                       // 8 MB
    unsigned short* Wb  = (unsigned short*)(ws + 8388608);           // 4 MB
    unsigned short* hb0 = (unsigned short*)(ws + 12582912);          // 128 KB
    unsigned short* hb1 = (unsigned short*)(ws + 12713984);          // 128 KB

    float* out     = (float*)d_out;                 // [64][512][1024]
    float* hn      = out + (size_t)NB * NT * NH;    // h_n region
    float* c_state = hn + (size_t)NB * NH;          // c_n region doubles as c state

    lstm_prep<<<1024, 256, 0, stream>>>(Ui, Uf, Uc, Uo, Wi, Wf, Wc, Wo,
                                        Ub, Wb, hb0, c_state);

    for (int t = 0; t < NT; t++) {
        unsigned short* hin  = (t & 1) ? hb1 : hb0;
        unsigned short* hout = (t & 1) ? hb0 : hb1;
        lstm_step<<<128, 256, 0, stream>>>(
            x, Ub, Wb, hin, hout, bi, bf, bc, bo,
            out, c_state, (t == NT - 1) ? hn : (float*)nullptr, t);
    }
}

// Round 2
// 8245.582 us; speedup vs baseline: 1.5448x; 1.5448x over previous
//
#include <hip/hip_runtime.h>
#include <hip/hip_bf16.h>

// LSTM B=64, T=512, I=512, H=1024.
// Fast path: persistent kernel, 64 WGs x 1024 thr, U slice resident in LDS (128KB,
// XOR-swizzled), h via device-scope atomics + per-step counter barrier, x pre-
// transposed/bf16-converted, c-state in registers. Fallback: round-1 per-step path.

typedef __attribute__((ext_vector_type(8))) short bf16x8;
typedef __attribute__((ext_vector_type(4))) float f32x4;
typedef unsigned int uint32;

static __device__ __forceinline__ unsigned short f2bf(float f) {
    union { float f; unsigned int u; } v; v.f = f;
    unsigned int r = v.u + 0x7fffu + ((v.u >> 16) & 1u);  // RNE
    return (unsigned short)(r >> 16);
}

#define NB   64
#define NT   512
#define NI   512
#define NH   1024
#define NWG  64

// ================= fast path =================

// prep: W f32->bf16 [4][1024][512]; x transpose+convert -> xT[t][b][i] bf16;
// zero h ping-pong buffers (packed uint) and barrier counters.
__global__ void prep_fast(const float* __restrict__ x,
                          const float* __restrict__ Wi, const float* __restrict__ Wf,
                          const float* __restrict__ Wc, const float* __restrict__ Wo,
                          unsigned short* __restrict__ Wb, unsigned short* __restrict__ xTb,
                          uint32* __restrict__ hb, int* __restrict__ arr)
{
    const int NW  = 4 * NH * NI;          // 2097152
    const int NX  = NB * NT * NI;         // 16777216
    const int NHB = 2 * NB * (NH / 2);    // 65536 uints (both h buffers)
    const int total = NW + NX + NHB + NT;
    for (int idx = blockIdx.x * blockDim.x + threadIdx.x; idx < total;
         idx += gridDim.x * blockDim.x) {
        if (idx < NW) {
            int g = idx >> 19;
            int off = idx & 524287;
            const float* W = (g == 0) ? Wi : (g == 1) ? Wf : (g == 2) ? Wc : Wo;
            Wb[idx] = f2bf(W[off]);
        } else if (idx < NW + NX) {
            int e = idx - NW;
            int b = e >> 18;              // T*I = 262144
            int r = e & 262143;
            int t = r >> 9;
            int i = r & 511;
            xTb[((size_t)t * NB + b) * NI + i] = f2bf(x[e]);
        } else if (idx < NW + NX + NHB) {
            hb[idx - NW - NX] = 0;
        } else {
            arr[idx - NW - NX - NHB] = 0;
        }
    }
}

__global__ __launch_bounds__(1024) void lstm_persist(
    const float* __restrict__ Ui, const float* __restrict__ Uf,
    const float* __restrict__ Uc, const float* __restrict__ Uo,
    const float* __restrict__ b_i, const float* __restrict__ b_f,
    const float* __restrict__ b_c, const float* __restrict__ b_o,
    const unsigned short* __restrict__ Wb, const unsigned short* __restrict__ xT,
    uint32* __restrict__ hb0, uint32* __restrict__ hb1,
    int* __restrict__ arr,
    float* __restrict__ out, float* __restrict__ hn_arr, float* __restrict__ cn_arr)
{
    __shared__ __align__(16) unsigned char smem[163840];   // exactly 160 KiB
    unsigned char* Us   = smem;                  // 64 rows x 2048B, swizzled bf16 U slice
    unsigned char* stg0 = smem + 131072;         // 16KB staging buf 0 (aliases gacc)
    unsigned char* stg1 = smem + 147456;         // 16KB staging buf 1
    float* gacc = (float*)(smem + 131072);       // [4][64][16] f32

    const int tid  = threadIdx.x;
    const int lane = tid & 63;
    const int wv   = tid >> 6;      // 0..15
    const int g    = wv & 3;        // gate
    const int mt   = wv >> 2;       // b-tile (16 rows)
    const int rm   = lane & 15;
    const int kg   = (lane >> 4) * 8;
    const int u0   = blockIdx.x * 16;

    // ---- prologue: fill U LDS slice (f32 -> bf16, XOR-swizzled rows) ----
    for (int i = 0; i < 8; ++i) {
        int unit = i * 1024 + tid;          // 16B units: 64 rows x 128
        int row  = unit >> 7;
        int k0   = (unit & 127) * 8;
        int gg   = row >> 4;
        const float* src = (gg == 0 ? Ui : gg == 1 ? Uf : gg == 2 ? Uc : Uo)
                           + (size_t)(u0 + (row & 15)) * NH + k0;
        bf16x8 v;
        #pragma unroll
        for (int j = 0; j < 8; ++j) v[j] = (short)f2bf(src[j]);
        *(bf16x8*)(Us + row * 2048 + ((k0 * 2) ^ ((row & 15) << 4))) = v;
    }

    const int bl = tid >> 4, ul = tid & 15;
    const float rbi = b_i[u0 + ul], rbf = b_f[u0 + ul];
    const float rbc = b_c[u0 + ul], rbo = b_o[u0 + ul];
    float creg = 0.f;

    // staging constants (thread tid stages 16B of row sb, k-offset k8 within chunk)
    const int sb   = bl;
    const int k8   = ul * 8;
    const int soff = sb * 256 + ((k8 * 2) ^ ((sb & 15) << 4));
    const size_t hrow = (size_t)sb * (NH / 2);

    const int abase = (mt * 16 + rm) * 256;
    const int ubase = (g * 16 + rm) * 2048;
    const size_t wrow = ((size_t)(g * NH + u0 + rm)) * NI;

    __syncthreads();

    for (int t = 0; t < NT; ++t) {
        const uint32* hin = (t & 1) ? hb1 : hb0;
        uint32* hout      = (t & 1) ? hb0 : hb1;
        const unsigned short* xrow = xT + ((size_t)t * NB + sb) * NI;

        f32x4 acc = {0.f, 0.f, 0.f, 0.f};
        uint32 rr[4][4];

        // prefetch chunks 0..3 (all h chunks) into registers
        #pragma unroll
        for (int c = 0; c < 4; ++c) {
            uint32* hp = (uint32*)(hin + hrow + (c * 128 + k8) / 2);
            #pragma unroll
            for (int j = 0; j < 4; ++j)
                rr[c][j] = __hip_atomic_load(hp + j, __ATOMIC_RELAXED,
                                             __HIP_MEMORY_SCOPE_AGENT);
        }
        // stage chunk 0
        {
            uint4 v; v.x = rr[0][0]; v.y = rr[0][1]; v.z = rr[0][2]; v.w = rr[0][3];
            *(uint4*)(stg0 + soff) = v;
        }
        __syncthreads();

        // 12 chunks of 128 k: c<8 -> recurrent (h x U_lds), c>=8 -> input (xT x W)
        #pragma unroll
        for (int c = 0; c < 12; ++c) {
            if (c + 4 < 12) {                       // issue load for chunk c+4
                const int cc = c + 4;
                if (cc < 8) {
                    uint32* hp = (uint32*)(hin + hrow + (cc * 128 + k8) / 2);
                    #pragma unroll
                    for (int j = 0; j < 4; ++j)
                        rr[cc & 3][j] = __hip_atomic_load(hp + j, __ATOMIC_RELAXED,
                                                          __HIP_MEMORY_SCOPE_AGENT);
                } else {
                    const uint4 v = *(const uint4*)(xrow + (cc - 8) * 128 + k8);
                    rr[cc & 3][0] = v.x; rr[cc & 3][1] = v.y;
                    rr[cc & 3][2] = v.z; rr[cc & 3][3] = v.w;
                }
            }
            // compute chunk c
            const unsigned char* sbuf = (c & 1) ? stg1 : stg0;
            #pragma unroll
            for (int kk = 0; kk < 4; ++kk) {
                const int kloc = kk * 32 + kg;
                bf16x8 af = *(const bf16x8*)(sbuf + abase + ((kloc * 2) ^ (rm << 4)));
                bf16x8 bfg;
                if (c < 8) {
                    const int kglob = c * 128 + kloc;
                    bfg = *(const bf16x8*)(Us + ubase + ((kglob * 2) ^ (rm << 4)));
                } else {
                    bfg = *(const bf16x8*)(Wb + wrow + (c - 8) * 128 + kloc);
                }
                acc = __builtin_amdgcn_mfma_f32_16x16x32_bf16(af, bfg, acc, 0, 0, 0);
            }
            // write staged chunk c+1
            if (c + 1 < 12) {
                unsigned char* dbuf = ((c + 1) & 1) ? stg1 : stg0;
                uint4 v; v.x = rr[(c + 1) & 3][0]; v.y = rr[(c + 1) & 3][1];
                v.z = rr[(c + 1) & 3][2]; v.w = rr[(c + 1) & 3][3];
                *(uint4*)(dbuf + soff) = v;
            }
            __syncthreads();
        }

        // exchange gate preactivations (C/D layout: col=lane&15, row=(lane>>4)*4+r)
        #pragma unroll
        for (int r = 0; r < 4; ++r) {
            const int brow = mt * 16 + (lane >> 4) * 4 + r;
            gacc[(g * 64 + brow) * 16 + rm] = acc[r];
        }
        __syncthreads();

        // pointwise: thread owns (b=bl, u=u0+ul); c-state in register
        {
            float pi = gacc[(0 * 64 + bl) * 16 + ul] + rbi;
            float pf = gacc[(1 * 64 + bl) * 16 + ul] + rbf;
            float pg = gacc[(2 * 64 + bl) * 16 + ul] + rbc;
            float po = gacc[(3 * 64 + bl) * 16 + ul] + rbo;
            float ig  = 1.f / (1.f + __expf(-pi));
            float fg  = 1.f / (1.f + __expf(-pf));
            float gg2 = tanhf(pg);
            float og  = 1.f / (1.f + __expf(-po));
            float cn2 = fg * creg + ig * gg2;
            float hn2 = og * tanhf(cn2);
            creg = cn2;
            out[((size_t)bl * NT + t) * NH + u0 + ul] = hn2;
            unsigned short h16 = f2bf(hn2);
            unsigned int other = ((unsigned int)__shfl_xor((int)h16, 1, 64)) & 0xffffu;
            if (!(ul & 1)) {
                uint32 pk = (uint32)h16 | (other << 16);
                __hip_atomic_store(hout + hrow + (u0 + ul) / 2, pk,
                                   __ATOMIC_RELAXED, __HIP_MEMORY_SCOPE_AGENT);
            }
            if (t == NT - 1) {
                hn_arr[(size_t)bl * NH + u0 + ul] = hn2;
                cn_arr[(size_t)bl * NH + u0 + ul] = cn2;
            }
        }

        // grid barrier: ping-pong h buffers => one barrier per step suffices
        __syncthreads();
        if (tid == 0) {
            __hip_atomic_fetch_add(&arr[t], 1, __ATOMIC_RELAXED,
                                   __HIP_MEMORY_SCOPE_AGENT);
            while (__hip_atomic_load(&arr[t], __ATOMIC_RELAXED,
                                     __HIP_MEMORY_SCOPE_AGENT) < NWG)
                __builtin_amdgcn_s_sleep(1);
        }
        __syncthreads();
    }
}

// ================= round-1 fallback (proven) =================

__global__ void lstm_prep(const float* __restrict__ Ui, const float* __restrict__ Uf,
                          const float* __restrict__ Uc, const float* __restrict__ Uo,
                          const float* __restrict__ Wi, const float* __restrict__ Wf,
                          const float* __restrict__ Wc, const float* __restrict__ Wo,
                          unsigned short* __restrict__ Ub, unsigned short* __restrict__ Wb,
                          unsigned short* __restrict__ hb0, float* __restrict__ c_state)
{
    const int NU = 4 * NH * NH;
    const int NW = 4 * NH * NI;
    const int NS = NB * NH;
    const int total = NU + NW + NS + NS;
    for (int idx = blockIdx.x * blockDim.x + threadIdx.x; idx < total;
         idx += gridDim.x * blockDim.x) {
        if (idx < NU) {
            int g = idx >> 20;
            int off = idx & (NH * NH - 1);
            const float* U = (g == 0) ? Ui : (g == 1) ? Uf : (g == 2) ? Uc : Uo;
            Ub[idx] = f2bf(U[off]);
        } else if (idx < NU + NW) {
            int j = idx - NU;
            int g = j >> 19;
            int off = j & (NH * NI - 1);
            const float* W = (g == 0) ? Wi : (g == 1) ? Wf : (g == 2) ? Wc : Wo;
            Wb[j] = f2bf(W[off]);
        } else if (idx < NU + NW + NS) {
            hb0[idx - NU - NW] = 0;
        } else {
            c_state[idx - NU - NW - NS] = 0.0f;
        }
    }
}

__global__ __launch_bounds__(256) void lstm_step(
    const float* __restrict__ x,
    const unsigned short* __restrict__ Ub,
    const unsigned short* __restrict__ Wb,
    const unsigned short* __restrict__ hb_in,
    unsigned short* __restrict__ hb_out,
    const float* __restrict__ bi, const float* __restrict__ bff,
    const float* __restrict__ bc, const float* __restrict__ bo,
    float* __restrict__ out, float* __restrict__ c_state,
    float* __restrict__ hn_out, int t)
{
    __shared__ float gacc[4][32][16];
    const int lane = threadIdx.x & 63;
    const int g    = threadIdx.x >> 6;
    const int u0   = (blockIdx.x >> 1) * 16;
    const int b0   = (blockIdx.x & 1) * 32;
    const int rm   = lane & 15;
    const int kg   = (lane >> 4) * 8;

    f32x4 acc0 = {0.f, 0.f, 0.f, 0.f};
    f32x4 acc1 = {0.f, 0.f, 0.f, 0.f};

    const unsigned short* Ug  = Ub + (size_t)g * (NH * NH) + (size_t)(u0 + rm) * NH;
    const unsigned short* h0p = hb_in + (size_t)(b0 + rm) * NH;
    const unsigned short* h1p = hb_in + (size_t)(b0 + 16 + rm) * NH;
    #pragma unroll 4
    for (int k0 = 0; k0 < NH; k0 += 32) {
        bf16x8 bfrag = *(const bf16x8*)(Ug + k0 + kg);
        bf16x8 a0 = *(const bf16x8*)(h0p + k0 + kg);
        bf16x8 a1 = *(const bf16x8*)(h1p + k0 + kg);
        acc0 = __builtin_amdgcn_mfma_f32_16x16x32_bf16(a0, bfrag, acc0, 0, 0, 0);
        acc1 = __builtin_amdgcn_mfma_f32_16x16x32_bf16(a1, bfrag, acc1, 0, 0, 0);
    }
    const unsigned short* Wg  = Wb + (size_t)g * (NH * NI) + (size_t)(u0 + rm) * NI;
    const float* x0p = x + ((size_t)(b0 + rm) * NT + t) * NI;
    const float* x1p = x + ((size_t)(b0 + 16 + rm) * NT + t) * NI;
    #pragma unroll 2
    for (int k0 = 0; k0 < NI; k0 += 32) {
        bf16x8 bfrag = *(const bf16x8*)(Wg + k0 + kg);
        f32x4 lo0 = *(const f32x4*)(x0p + k0 + kg);
        f32x4 hi0 = *(const f32x4*)(x0p + k0 + kg + 4);
        f32x4 lo1 = *(const f32x4*)(x1p + k0 + kg);
        f32x4 hi1 = *(const f32x4*)(x1p + k0 + kg + 4);
        bf16x8 a0, a1;
        #pragma unroll
        for (int j = 0; j < 4; j++) {
            a0[j]     = (short)f2bf(lo0[j]);
            a0[j + 4] = (short)f2bf(hi0[j]);
            a1[j]     = (short)f2bf(lo1[j]);
            a1[j + 4] = (short)f2bf(hi1[j]);
        }
        acc0 = __builtin_amdgcn_mfma_f32_16x16x32_bf16(a0, bfrag, acc0, 0, 0, 0);
        acc1 = __builtin_amdgcn_mfma_f32_16x16x32_bf16(a1, bfrag, acc1, 0, 0, 0);
    }
    const int row4 = (lane >> 4) * 4;
    #pragma unroll
    for (int r = 0; r < 4; r++) {
        gacc[g][row4 + r][rm]      = acc0[r];
        gacc[g][16 + row4 + r][rm] = acc1[r];
    }
    __syncthreads();
    for (int p = threadIdx.x; p < 512; p += 256) {
        int bl = p >> 4, ul = p & 15;
        int b = b0 + bl, u = u0 + ul;
        float pi = gacc[0][bl][ul] + bi[u];
        float pf = gacc[1][bl][ul] + bff[u];
        float pg = gacc[2][bl][ul] + bc[u];
        float po = gacc[3][bl][ul] + bo[u];
        float ig = 1.f / (1.f + __expf(-pi));
        float fg = 1.f / (1.f + __expf(-pf));
        float gg = tanhf(pg);
        float og = 1.f / (1.f + __expf(-po));
        float cold = c_state[(size_t)b * NH + u];
        float cn = fg * cold + ig * gg;
        float hn = og * tanhf(cn);
        c_state[(size_t)b * NH + u] = cn;
        out[((size_t)b * NT + t) * NH + u] = hn;
        hb_out[(size_t)b * NH + u] = f2bf(hn);
        if (hn_out) hn_out[(size_t)b * NH + u] = hn;
    }
}

// ================= launch =================

extern "C" void kernel_launch(void* const* d_in, const int* in_sizes, int n_in,
                              void* d_out, int out_size, void* d_ws, size_t ws_size,
                              hipStream_t stream) {
    const float* x  = (const float*)d_in[0];
    const float* Wi = (const float*)d_in[1];
    const float* Wf = (const float*)d_in[2];
    const float* Wc = (const float*)d_in[3];
    const float* Wo = (const float*)d_in[4];
    const float* Ui = (const float*)d_in[5];
    const float* Uf = (const float*)d_in[6];
    const float* Uc = (const float*)d_in[7];
    const float* Uo = (const float*)d_in[8];
    const float* bi = (const float*)d_in[9];
    const float* bf = (const float*)d_in[10];
    const float* bc = (const float*)d_in[11];
    const float* bo = (const float*)d_in[12];

    float* out = (float*)d_out;
    float* hn  = out + (size_t)NB * NT * NH;
    float* cn  = hn + (size_t)NB * NH;

    const size_t NEED = 38012928ULL;   // Wb 4MB + xT 32MB + h bufs 256KB + arr 2KB
    if (ws_size >= NEED) {
        char* ws = (char*)d_ws;
        unsigned short* Wb = (unsigned short*)ws;
        unsigned short* xT = (unsigned short*)(ws + 4194304);
        uint32* hb0 = (uint32*)(ws + 37748736);
        uint32* hb1 = (uint32*)(ws + 37748736 + 131072);
        int* arr    = (int*)(ws + 38010880);
        prep_fast<<<2048, 256, 0, stream>>>(x, Wi, Wf, Wc, Wo, Wb, xT, hb0, arr);
        lstm_persist<<<NWG, 1024, 0, stream>>>(Ui, Uf, Uc, Uo, bi, bf, bc, bo,
                                               Wb, xT, hb0, hb1, arr, out, hn, cn);
    } else {
        char* ws = (char*)d_ws;
        unsigned short* Ub  = (unsigned short*)ws;
        unsigned short* Wb  = (unsigned short*)(ws + 8388608);
        unsigned short* hb0 = (unsigned short*)(ws + 12582912);
        unsigned short* hb1 = (unsigned short*)(ws + 12713984);
        float* c_state = cn;
        lstm_prep<<<1024, 256, 0, stream>>>(Ui, Uf, Uc, Uo, Wi, Wf, Wc, Wo,
                                            Ub, Wb, hb0, c_state);
        for (int t = 0; t < NT; t++) {
            unsigned short* hin  = (t & 1) ? hb1 : hb0;
            unsigned short* hout = (t & 1) ? hb0 : hb1;
            lstm_step<<<128, 256, 0, stream>>>(
                x, Ub, Wb, hin, hout, bi, bf, bc, bo,
                out, c_state, (t == NT - 1) ? hn : (float*)nullptr, t);
        }
    }
}

// Round 3
// 6837.947 us; speedup vs baseline: 1.8629x; 1.2059x over previous
//
#include <hip/hip_runtime.h>
#include <hip/hip_bf16.h>

// LSTM B=64, T=512, I=512, H=1024.
// Persistent kernel, 64 WGs x 1024 thr, 1 WG/CU (160KB LDS).
// U slice (64x1024 bf16, XOR-swizzled) resident in LDS for all 512 steps.
// h exchange: packed u64 sc1 atomic stores -> 3 rotating buffers; per-WG flag
// lines polled by one wave (64 parallel line reads, no centralized RMW barrier).
// x-part computed before the flag wait (overlaps flag propagation).

typedef __attribute__((ext_vector_type(8))) short bf16x8;
typedef __attribute__((ext_vector_type(4))) float f32x4;
typedef unsigned int uint32;
typedef unsigned long long u64;

static __device__ __forceinline__ unsigned short f2bf(float f) {
    union { float f; unsigned int u; } v; v.f = f;
    unsigned int r = v.u + 0x7fffu + ((v.u >> 16) & 1u);  // RNE
    return (unsigned short)(r >> 16);
}

#define NB   64
#define NT   512
#define NI   512
#define NH   1024
#define NWG  64

// ================= fast path =================

// prep: W f32->bf16 [4][1024][512]; x transpose+convert -> xT[t][b][i] bf16;
// zero flag region (poison 0xAA must not look like a set flag).
__global__ void prep3(const float* __restrict__ x,
                      const float* __restrict__ Wi, const float* __restrict__ Wf,
                      const float* __restrict__ Wc, const float* __restrict__ Wo,
                      unsigned short* __restrict__ Wb, unsigned short* __restrict__ xTb,
                      int* __restrict__ flags)
{
    const int NW = 4 * NH * NI;          // 2097152
    const int NX = NB * NT * NI;         // 16777216
    const int NF = NT * 1024;            // 524288 ints (flag lines, 64B/WG/step)
    const int total = NW + NX + NF;
    for (int idx = blockIdx.x * blockDim.x + threadIdx.x; idx < total;
         idx += gridDim.x * blockDim.x) {
        if (idx < NW) {
            int g = idx >> 19;
            int off = idx & 524287;
            const float* W = (g == 0) ? Wi : (g == 1) ? Wf : (g == 2) ? Wc : Wo;
            Wb[idx] = f2bf(W[off]);
        } else if (idx < NW + NX) {
            int e = idx - NW;
            int b = e >> 18;              // T*I = 262144
            int r = e & 262143;
            int t = r >> 9;
            int i = r & 511;
            xTb[((size_t)t * NB + b) * NI + i] = f2bf(x[e]);
        } else {
            flags[idx - NW - NX] = 0;
        }
    }
}

__global__ __launch_bounds__(1024) void lstm_persist3(
    const float* __restrict__ Ui, const float* __restrict__ Uf,
    const float* __restrict__ Uc, const float* __restrict__ Uo,
    const float* __restrict__ b_i, const float* __restrict__ b_f,
    const float* __restrict__ b_c, const float* __restrict__ b_o,
    const unsigned short* __restrict__ Wb, const unsigned short* __restrict__ xT,
    unsigned short* __restrict__ hb,      // 3 rotating [64][1024] bf16 buffers
    int* __restrict__ flags,              // [NT][64 wg][16 ints] (64B lines)
    float* __restrict__ out, float* __restrict__ hn_arr, float* __restrict__ cn_arr)
{
    __shared__ __align__(16) unsigned char smem[163840];   // exactly 160 KiB
    unsigned char* Us   = smem;                  // 64 rows x 2048B swizzled U slice
    unsigned char* stg0 = smem + 131072;         // 16KB staging buf 0 (aliases gacc)
    unsigned char* stg1 = smem + 147456;         // 16KB staging buf 1
    float* gacc = (float*)(smem + 131072);       // [4][64][16] f32

    const int tid  = threadIdx.x;
    const int lane = tid & 63;
    const int wv   = tid >> 6;      // 0..15
    const int g    = wv & 3;        // gate
    const int mt   = wv >> 2;       // b-tile (16 rows)
    const int rm   = lane & 15;
    const int kg   = (lane >> 4) * 8;
    const int wg   = blockIdx.x;
    const int u0   = wg * 16;

    // ---- prologue: fill U LDS slice (f32 -> bf16, XOR-swizzled rows) ----
    for (int i = 0; i < 8; ++i) {
        int unit = i * 1024 + tid;          // 16B units: 64 rows x 128
        int row  = unit >> 7;
        int k0   = (unit & 127) * 8;
        int gg   = row >> 4;
        const float* src = (gg == 0 ? Ui : gg == 1 ? Uf : gg == 2 ? Uc : Uo)
                           + (size_t)(u0 + (row & 15)) * NH + k0;
        bf16x8 v;
        #pragma unroll
        for (int j = 0; j < 8; ++j) v[j] = (short)f2bf(src[j]);
        *(bf16x8*)(Us + row * 2048 + ((k0 * 2) ^ ((row & 15) << 4))) = v;
    }

    const int bl = tid >> 4, ul = tid & 15;
    const float rbi = b_i[u0 + ul], rbf = b_f[u0 + ul];
    const float rbc = b_c[u0 + ul], rbo = b_o[u0 + ul];
    float creg = 0.f;

    // staging constants: thread stages 16B of row sb, k-offset k8 within a chunk
    const int sb   = bl;
    const int k8   = ul * 8;
    const int soff = sb * 256 + ((k8 * 2) ^ ((sb & 15) << 4));

    const int abase = (mt * 16 + rm) * 256;
    const int ubase = (g * 16 + rm) * 2048;
    const size_t wrow = ((size_t)(g * NH + u0 + rm)) * NI;

    __syncthreads();

    for (int t = 0; t < NT; ++t) {
        f32x4 acc = {0.f, 0.f, 0.f, 0.f};

        // ================= X part (no h dependency) =================
        const unsigned short* xrow = xT + ((size_t)t * NB + sb) * NI;
        uint4 xr[4];
        #pragma unroll
        for (int c = 0; c < 4; ++c)
            xr[c] = *(const uint4*)(xrow + c * 128 + k8);
        *(uint4*)(stg0 + soff) = xr[0];
        __syncthreads();
        #pragma unroll
        for (int c = 0; c < 4; ++c) {
            const unsigned char* sbuf = (c & 1) ? stg1 : stg0;
            #pragma unroll
            for (int kk = 0; kk < 4; ++kk) {
                const int kloc = kk * 32 + kg;
                bf16x8 af = *(const bf16x8*)(sbuf + abase + ((kloc * 2) ^ (rm << 4)));
                bf16x8 bw = *(const bf16x8*)(Wb + wrow + c * 128 + kloc);
                acc = __builtin_amdgcn_mfma_f32_16x16x32_bf16(af, bw, acc, 0, 0, 0);
            }
            if (c < 3) {
                unsigned char* dbuf = ((c + 1) & 1) ? stg1 : stg0;
                *(uint4*)(dbuf + soff) = xr[c + 1];
            }
            __syncthreads();
        }

        // ================= H part =================
        if (t > 0) {
            // wait for all producers of step t-1 (64 parallel flag-line reads)
            if (wv == 0) {
                const int* fp = flags + (size_t)(t - 1) * 1024 + lane * 16;
                int spins = 0;
                while (__hip_atomic_load(fp, __ATOMIC_RELAXED,
                                         __HIP_MEMORY_SCOPE_AGENT) == 0 &&
                       spins < (1 << 20)) {
                    __builtin_amdgcn_s_sleep(2);
                    ++spins;
                }
            }
            __syncthreads();

            // issue ALL h loads upfront (one exposed L3 roundtrip)
            const u64* hsrc = (const u64*)hb + (size_t)((t - 1) % 3) * 16384
                              + (size_t)sb * 256 + (size_t)ul * 2;
            u64 hr[8][2];
            #pragma unroll
            for (int c = 0; c < 8; ++c) {
                hr[c][0] = __hip_atomic_load(hsrc + c * 32, __ATOMIC_RELAXED,
                                             __HIP_MEMORY_SCOPE_AGENT);
                hr[c][1] = __hip_atomic_load(hsrc + c * 32 + 1, __ATOMIC_RELAXED,
                                             __HIP_MEMORY_SCOPE_AGENT);
            }
            {
                uint4 v; v.x = (uint32)hr[0][0]; v.y = (uint32)(hr[0][0] >> 32);
                v.z = (uint32)hr[0][1]; v.w = (uint32)(hr[0][1] >> 32);
                *(uint4*)(stg0 + soff) = v;
            }
            __syncthreads();
            #pragma unroll
            for (int c = 0; c < 8; ++c) {
                const unsigned char* sbuf = (c & 1) ? stg1 : stg0;
                #pragma unroll
                for (int kk = 0; kk < 4; ++kk) {
                    const int kloc = kk * 32 + kg;
                    bf16x8 af = *(const bf16x8*)(sbuf + abase + ((kloc * 2) ^ (rm << 4)));
                    const int kglob = c * 128 + kloc;
                    bf16x8 bu = *(const bf16x8*)(Us + ubase + ((kglob * 2) ^ (rm << 4)));
                    acc = __builtin_amdgcn_mfma_f32_16x16x32_bf16(af, bu, acc, 0, 0, 0);
                }
                if (c < 7) {
                    unsigned char* dbuf = ((c + 1) & 1) ? stg1 : stg0;
                    uint4 v; v.x = (uint32)hr[c + 1][0]; v.y = (uint32)(hr[c + 1][0] >> 32);
                    v.z = (uint32)hr[c + 1][1]; v.w = (uint32)(hr[c + 1][1] >> 32);
                    *(uint4*)(dbuf + soff) = v;
                }
                __syncthreads();
            }
        }

        // ======= gate exchange (C/D layout: col=lane&15, row=(lane>>4)*4+r) =======
        #pragma unroll
        for (int r = 0; r < 4; ++r) {
            const int brow = mt * 16 + (lane >> 4) * 4 + r;
            gacc[(g * 64 + brow) * 16 + rm] = acc[r];
        }
        __syncthreads();

        // ======= pointwise: thread owns (b=bl, u=u0+ul); c-state in register =======
        {
            float pi = gacc[(0 * 64 + bl) * 16 + ul] + rbi;
            float pf = gacc[(1 * 64 + bl) * 16 + ul] + rbf;
            float pg = gacc[(2 * 64 + bl) * 16 + ul] + rbc;
            float po = gacc[(3 * 64 + bl) * 16 + ul] + rbo;
            float ig  = 1.f / (1.f + __expf(-pi));
            float fg  = 1.f / (1.f + __expf(-pf));
            float gg2 = tanhf(pg);
            float og  = 1.f / (1.f + __expf(-po));
            float cn2 = fg * creg + ig * gg2;
            float hn2 = og * tanhf(cn2);
            creg = cn2;
            out[((size_t)bl * NT + t) * NH + u0 + ul] = hn2;

            // pack 4 consecutive u into one u64, sc1 store to rotating h buffer
            unsigned short h16 = f2bf(hn2);
            uint32 lo = (uint32)h16 |
                        ((((uint32)__shfl_down((int)h16, 1, 64)) & 0xffffu) << 16);
            u64 p4 = (u64)lo | ((u64)(uint32)__shfl_down((int)lo, 2, 64) << 32);
            if ((ul & 3) == 0) {
                u64* hd = (u64*)hb + (size_t)(t % 3) * 16384
                          + (size_t)bl * 256 + (size_t)((u0 + ul) >> 2);
                __hip_atomic_store(hd, p4, __ATOMIC_RELAXED,
                                   __HIP_MEMORY_SCOPE_AGENT);
            }
            if (t == NT - 1) {
                hn_arr[(size_t)bl * NH + u0 + ul] = hn2;
                cn_arr[(size_t)bl * NH + u0 + ul] = cn2;
            }
        }

        // barrier drains vmcnt -> h stores acked at coherence point; then flag
        __syncthreads();
        if (tid == 0)
            __hip_atomic_store(flags + (size_t)t * 1024 + wg * 16, 1,
                               __ATOMIC_RELAXED, __HIP_MEMORY_SCOPE_AGENT);
    }
}

// ================= round-1 fallback (proven) =================

__global__ void lstm_prep(const float* __restrict__ Ui, const float* __restrict__ Uf,
                          const float* __restrict__ Uc, const float* __restrict__ Uo,
                          const float* __restrict__ Wi, const float* __restrict__ Wf,
                          const float* __restrict__ Wc, const float* __restrict__ Wo,
                          unsigned short* __restrict__ Ub, unsigned short* __restrict__ Wb,
                          unsigned short* __restrict__ hb0, float* __restrict__ c_state)
{
    const int NU = 4 * NH * NH;
    const int NW = 4 * NH * NI;
    const int NS = NB * NH;
    const int total = NU + NW + NS + NS;
    for (int idx = blockIdx.x * blockDim.x + threadIdx.x; idx < total;
         idx += gridDim.x * blockDim.x) {
        if (idx < NU) {
            int g = idx >> 20;
            int off = idx & (NH * NH - 1);
            const float* U = (g == 0) ? Ui : (g == 1) ? Uf : (g == 2) ? Uc : Uo;
            Ub[idx] = f2bf(U[off]);
        } else if (idx < NU + NW) {
            int j = idx - NU;
            int g = j >> 19;
            int off = j & (NH * NI - 1);
            const float* W = (g == 0) ? Wi : (g == 1) ? Wf : (g == 2) ? Wc : Wo;
            Wb[j] = f2bf(W[off]);
        } else if (idx < NU + NW + NS) {
            hb0[idx - NU - NW] = 0;
        } else {
            c_state[idx - NU - NW - NS] = 0.0f;
        }
    }
}

__global__ __launch_bounds__(256) void lstm_step(
    const float* __restrict__ x,
    const unsigned short* __restrict__ Ub,
    const unsigned short* __restrict__ Wb,
    const unsigned short* __restrict__ hb_in,
    unsigned short* __restrict__ hb_out,
    const float* __restrict__ bi, const float* __restrict__ bff,
    const float* __restrict__ bc, const float* __restrict__ bo,
    float* __restrict__ out, float* __restrict__ c_state,
    float* __restrict__ hn_out, int t)
{
    __shared__ float gacc[4][32][16];
    const int lane = threadIdx.x & 63;
    const int g    = threadIdx.x >> 6;
    const int u0   = (blockIdx.x >> 1) * 16;
    const int b0   = (blockIdx.x & 1) * 32;
    const int rm   = lane & 15;
    const int kg   = (lane >> 4) * 8;

    f32x4 acc0 = {0.f, 0.f, 0.f, 0.f};
    f32x4 acc1 = {0.f, 0.f, 0.f, 0.f};

    const unsigned short* Ug  = Ub + (size_t)g * (NH * NH) + (size_t)(u0 + rm) * NH;
    const unsigned short* h0p = hb_in + (size_t)(b0 + rm) * NH;
    const unsigned short* h1p = hb_in + (size_t)(b0 + 16 + rm) * NH;
    #pragma unroll 4
    for (int k0 = 0; k0 < NH; k0 += 32) {
        bf16x8 bfrag = *(const bf16x8*)(Ug + k0 + kg);
        bf16x8 a0 = *(const bf16x8*)(h0p + k0 + kg);
        bf16x8 a1 = *(const bf16x8*)(h1p + k0 + kg);
        acc0 = __builtin_amdgcn_mfma_f32_16x16x32_bf16(a0, bfrag, acc0, 0, 0, 0);
        acc1 = __builtin_amdgcn_mfma_f32_16x16x32_bf16(a1, bfrag, acc1, 0, 0, 0);
    }
    const unsigned short* Wg  = Wb + (size_t)g * (NH * NI) + (size_t)(u0 + rm) * NI;
    const float* x0p = x + ((size_t)(b0 + rm) * NT + t) * NI;
    const float* x1p = x + ((size_t)(b0 + 16 + rm) * NT + t) * NI;
    #pragma unroll 2
    for (int k0 = 0; k0 < NI; k0 += 32) {
        bf16x8 bfrag = *(const bf16x8*)(Wg + k0 + kg);
        f32x4 lo0 = *(const f32x4*)(x0p + k0 + kg);
        f32x4 hi0 = *(const f32x4*)(x0p + k0 + kg + 4);
        f32x4 lo1 = *(const f32x4*)(x1p + k0 + kg);
        f32x4 hi1 = *(const f32x4*)(x1p + k0 + kg + 4);
        bf16x8 a0, a1;
        #pragma unroll
        for (int j = 0; j < 4; j++) {
            a0[j]     = (short)f2bf(lo0[j]);
            a0[j + 4] = (short)f2bf(hi0[j]);
            a1[j]     = (short)f2bf(lo1[j]);
            a1[j + 4] = (short)f2bf(hi1[j]);
        }
        acc0 = __builtin_amdgcn_mfma_f32_16x16x32_bf16(a0, bfrag, acc0, 0, 0, 0);
        acc1 = __builtin_amdgcn_mfma_f32_16x16x32_bf16(a1, bfrag, acc1, 0, 0, 0);
    }
    const int row4 = (lane >> 4) * 4;
    #pragma unroll
    for (int r = 0; r < 4; r++) {
        gacc[g][row4 + r][rm]      = acc0[r];
        gacc[g][16 + row4 + r][rm] = acc1[r];
    }
    __syncthreads();
    for (int p = threadIdx.x; p < 512; p += 256) {
        int bl = p >> 4, ul = p & 15;
        int b = b0 + bl, u = u0 + ul;
        float pi = gacc[0][bl][ul] + bi[u];
        float pf = gacc[1][bl][ul] + bff[u];
        float pg = gacc[2][bl][ul] + bc[u];
        float po = gacc[3][bl][ul] + bo[u];
        float ig = 1.f / (1.f + __expf(-pi));
        float fg = 1.f / (1.f + __expf(-pf));
        float gg = tanhf(pg);
        float og = 1.f / (1.f + __expf(-po));
        float cold = c_state[(size_t)b * NH + u];
        float cn = fg * cold + ig * gg;
        float hn = og * tanhf(cn);
        c_state[(size_t)b * NH + u] = cn;
        out[((size_t)b * NT + t) * NH + u] = hn;
        hb_out[(size_t)b * NH + u] = f2bf(hn);
        if (hn_out) hn_out[(size_t)b * NH + u] = hn;
    }
}

// ================= launch =================

extern "C" void kernel_launch(void* const* d_in, const int* in_sizes, int n_in,
                              void* d_out, int out_size, void* d_ws, size_t ws_size,
                              hipStream_t stream) {
    const float* x  = (const float*)d_in[0];
    const float* Wi = (const float*)d_in[1];
    const float* Wf = (const float*)d_in[2];
    const float* Wc = (const float*)d_in[3];
    const float* Wo = (const float*)d_in[4];
    const float* Ui = (const float*)d_in[5];
    const float* Uf = (const float*)d_in[6];
    const float* Uc = (const float*)d_in[7];
    const float* Uo = (const float*)d_in[8];
    const float* bi = (const float*)d_in[9];
    const float* bf = (const float*)d_in[10];
    const float* bc = (const float*)d_in[11];
    const float* bo = (const float*)d_in[12];

    float* out = (float*)d_out;
    float* hn  = out + (size_t)NB * NT * NH;
    float* cn  = hn + (size_t)NB * NH;

    // ws layout (fast path): Wb 4MB | xT 32MB | hb 3x128KB | flags 2MB
    const size_t NEED3 = 40239104ULL;
    if (ws_size >= NEED3) {
        char* ws = (char*)d_ws;
        unsigned short* Wb = (unsigned short*)ws;
        unsigned short* xT = (unsigned short*)(ws + 4194304);
        unsigned short* hb = (unsigned short*)(ws + 37748736);
        int* flags         = (int*)(ws + 38141952);
        prep3<<<2048, 256, 0, stream>>>(x, Wi, Wf, Wc, Wo, Wb, xT, flags);
        lstm_persist3<<<NWG, 1024, 0, stream>>>(Ui, Uf, Uc, Uo, bi, bf, bc, bo,
                                                Wb, xT, hb, flags, out, hn, cn);
    } else {
        char* ws = (char*)d_ws;
        unsigned short* Ub  = (unsigned short*)ws;
        unsigned short* Wb  = (unsigned short*)(ws + 8388608);
        unsigned short* hb0 = (unsigned short*)(ws + 12582912);
        unsigned short* hb1 = (unsigned short*)(ws + 12713984);
        float* c_state = cn;
        lstm_prep<<<1024, 256, 0, stream>>>(Ui, Uf, Uc, Uo, Wi, Wf, Wc, Wo,
                                            Ub, Wb, hb0, c_state);
        for (int t = 0; t < NT; t++) {
            unsigned short* hin  = (t & 1) ? hb1 : hb0;
            unsigned short* hout = (t & 1) ? hb0 : hb1;
            lstm_step<<<128, 256, 0, stream>>>(
                x, Ub, Wb, hin, hout, bi, bf, bc, bo,
                out, c_state, (t == NT - 1) ? hn : (float*)nullptr, t);
        }
    }
}